// Round 1
// baseline (136.004 us; speedup 1.0000x reference)
//
#include <hip/hip_runtime.h>
#include <math.h>

// Problem constants (from reference): N=500000, S=128, H=64.
// scores_i = x_i . u  (u = embed_w @ (key_w @ wk)); additive constants cancel in softmax.
// weighted_embedding = (sum_i w_i x_i) @ embed_w + embed_b  (emb is affine in x, sum w = 1).

#define S_DIM 128
#define H_DIM 64
#define NBLK  2048   // pass1 grid

// ---------------- pass 0: u[128] = embed_w @ (key_w @ wk) ----------------
__global__ void k_precompute_u(const float* __restrict__ embed_w,  // [128][64]
                               const float* __restrict__ key_w,    // [64][64]
                               const float* __restrict__ attn_w,   // [128][1]; wk = attn_w[64..127]
                               float* __restrict__ u)              // [128]
{
    __shared__ float kv[H_DIM];
    const int t = threadIdx.x; // 0..127
    if (t < H_DIM) {
        float acc = 0.f;
        #pragma unroll 8
        for (int j = 0; j < H_DIM; ++j) acc += key_w[t * H_DIM + j] * attn_w[H_DIM + j];
        kv[t] = acc;
    }
    __syncthreads();
    float acc = 0.f;
    #pragma unroll 8
    for (int h = 0; h < H_DIM; ++h) acc += embed_w[t * H_DIM + h] * kv[h];
    u[t] = acc;
}

// ---------------- pass 1: stream X; scores -> out_w; online (m,Z,t) partials ----------------
__global__ __launch_bounds__(256) void k_pass1(
    const float* __restrict__ X,        // [N][128]
    const float* __restrict__ u,        // [128]
    float* __restrict__ scores_out,     // [N]  (aliases d_out+64)
    float* __restrict__ pm,             // [NBLK]
    float* __restrict__ pz,             // [NBLK]
    float* __restrict__ pt,             // [NBLK][128]
    int N)
{
    const int lane = threadIdx.x & 63;
    const int w    = threadIdx.x >> 6;              // wave index in block (0..3)
    const int gw   = blockIdx.x * 4 + w;            // global wave
    const int W    = gridDim.x * 4;                 // total waves

    const float2 u2 = *(const float2*)(u + 2 * lane);

    float  m = -1e30f, Z = 0.f;
    float2 t = make_float2(0.f, 0.f);

    for (int r = gw; r < N; r += W) {
        const float2 x = *(const float2*)(X + (size_t)r * S_DIM + 2 * lane);
        float p = x.x * u2.x + x.y * u2.y;
        // 64-lane butterfly sum (bit-exact identical on every lane -> uniform branch below)
        p += __shfl_xor(p, 1);
        p += __shfl_xor(p, 2);
        p += __shfl_xor(p, 4);
        p += __shfl_xor(p, 8);
        p += __shfl_xor(p, 16);
        p += __shfl_xor(p, 32);
        const float s = p;
        if (lane == 0) scores_out[r] = s;
        if (s > m) {
            const float rs = __expf(m - s);   // exp(-1e30)=0 on first row
            Z = Z * rs + 1.f;
            t.x = t.x * rs + x.x;
            t.y = t.y * rs + x.y;
            m = s;
        } else {
            const float e = __expf(s - m);
            Z += e;
            t.x += e * x.x;
            t.y += e * x.y;
        }
    }

    // block-level merge of 4 waves
    __shared__ float sm[4], sZ[4];
    __shared__ float sT[4][S_DIM];
    sT[w][2 * lane]     = t.x;
    sT[w][2 * lane + 1] = t.y;
    if (lane == 0) { sm[w] = m; sZ[w] = Z; }
    __syncthreads();

    const float mb = fmaxf(fmaxf(sm[0], sm[1]), fmaxf(sm[2], sm[3]));
    const int k = threadIdx.x;
    if (k < S_DIM) {
        float acc = 0.f;
        #pragma unroll
        for (int ww = 0; ww < 4; ++ww) acc += sT[ww][k] * __expf(sm[ww] - mb);
        pt[(size_t)blockIdx.x * S_DIM + k] = acc;
    }
    if (k == 0) {
        float Zb = 0.f;
        #pragma unroll
        for (int ww = 0; ww < 4; ++ww) Zb += sZ[ww] * __expf(sm[ww] - mb);
        pm[blockIdx.x] = mb;
        pz[blockIdx.x] = Zb;
    }
}

// ---------------- pass 2: reduce partials; emit weighted_embedding + (m*,Z*) ----------------
__global__ __launch_bounds__(256) void k_pass2(
    const float* __restrict__ pm, const float* __restrict__ pz, const float* __restrict__ pt,
    const float* __restrict__ embed_w, const float* __restrict__ embed_b,
    float* __restrict__ out_emb,   // d_out[0..63]
    float* __restrict__ mz,        // [2] = {m*, Z*}
    int B)
{
    __shared__ float scale[NBLK];
    __shared__ float red[256];
    __shared__ float tS[S_DIM];
    const int tid = threadIdx.x;

    // global max
    float m = -1e30f;
    for (int b = tid; b < B; b += 256) m = fmaxf(m, pm[b]);
    red[tid] = m; __syncthreads();
    for (int s2 = 128; s2 > 0; s2 >>= 1) {
        if (tid < s2) red[tid] = fmaxf(red[tid], red[tid + s2]);
        __syncthreads();
    }
    const float mstar = red[0];
    __syncthreads();

    // scales + Z*
    float z = 0.f;
    for (int b = tid; b < B; b += 256) {
        const float sc = __expf(pm[b] - mstar);
        scale[b] = sc;
        z += pz[b] * sc;
    }
    red[tid] = z; __syncthreads();
    for (int s2 = 128; s2 > 0; s2 >>= 1) {
        if (tid < s2) red[tid] += red[tid + s2];
        __syncthreads();
    }
    const float Zstar = red[0];
    if (tid == 0) { mz[0] = mstar; mz[1] = Zstar; }
    __syncthreads();

    // t* (normalized)
    if (tid < S_DIM) {
        float acc = 0.f;
        for (int b = 0; b < B; ++b) acc += pt[(size_t)b * S_DIM + tid] * scale[b];
        tS[tid] = acc / Zstar;
    }
    __syncthreads();

    // weighted_embedding[h] = sum_k tS[k] * W[k][h] + b[h]
    if (tid < H_DIM) {
        float acc = embed_b[tid];
        #pragma unroll 8
        for (int k = 0; k < S_DIM; ++k) acc += tS[k] * embed_w[k * H_DIM + tid];
        out_emb[tid] = acc;
    }
}

// ---------------- pass 3: weights = exp(s - m*)/Z*, in place over d_out[64..] ----------------
__global__ __launch_bounds__(256) void k_pass3(
    float* __restrict__ sw, const float* __restrict__ mz, int N)
{
    const float mstar = mz[0];
    const float invZ  = 1.0f / mz[1];
    const int stride = gridDim.x * blockDim.x;
    for (int i = blockIdx.x * blockDim.x + threadIdx.x; i < N; i += stride)
        sw[i] = __expf(sw[i] - mstar) * invZ;
}

extern "C" void kernel_launch(void* const* d_in, const int* in_sizes, int n_in,
                              void* d_out, int out_size, void* d_ws, size_t ws_size,
                              hipStream_t stream) {
    const float* X       = (const float*)d_in[1];   // neighbor_states [N][128]
    const float* embed_w = (const float*)d_in[2];   // [128][64]
    const float* embed_b = (const float*)d_in[3];   // [64]
    const float* key_w   = (const float*)d_in[4];   // [64][64]
    const float* attn_w  = (const float*)d_in[8];   // [128][1]
    float* out = (float*)d_out;                     // [64 + N] fp32

    const int N = in_sizes[1] / S_DIM;              // 500000

    // workspace layout (floats): u[128] | mz[2] | pad | pm[NBLK] | pz[NBLK] | pt[NBLK*128]
    float* ws = (float*)d_ws;
    float* u  = ws;             // 128
    float* mz = ws + 128;       // 2
    float* pm = ws + 256;       // NBLK
    float* pz = pm + NBLK;      // NBLK
    float* pt = pz + NBLK;      // NBLK*128
    // total: 256 + 2048 + 2048 + 262144 floats ~= 1.07 MB

    float* out_emb = out;       // [64]
    float* out_w   = out + H_DIM; // [N] — pass1 parks raw scores here, pass3 rewrites in place

    k_precompute_u<<<1, 128, 0, stream>>>(embed_w, key_w, attn_w, u);
    k_pass1<<<NBLK, 256, 0, stream>>>(X, u, out_w, pm, pz, pt, N);
    k_pass2<<<1, 256, 0, stream>>>(pm, pz, pt, embed_w, embed_b, out_emb, mz, NBLK);
    k_pass3<<<2048, 256, 0, stream>>>(out_w, mz, N);
}

// Round 2
// 65.665 us; speedup vs baseline: 2.0712x; 2.0712x over previous
//
#include <hip/hip_runtime.h>
#include <math.h>

// N=500000, S=128, H=64.
// scores_i = x_i . u  (u = embed_w @ (key_w @ wk)); additive constants cancel in softmax.
// weighted_embedding = (sum_i w_i x_i) @ embed_w + embed_b  (affine in x, sum w = 1).

#define S_DIM 128
#define H_DIM 64
#define NBLK  2048   // pass1 grid

// ---------------- pass 0: u[128] = embed_w @ (key_w @ wk) ----------------
__global__ void k_precompute_u(const float* __restrict__ embed_w,  // [128][64]
                               const float* __restrict__ key_w,    // [64][64]
                               const float* __restrict__ attn_w,   // [128][1]; wk = attn_w[64..]
                               float* __restrict__ u)              // [128]
{
    __shared__ float kv[H_DIM];
    const int t = threadIdx.x; // 0..127
    if (t < H_DIM) {
        float acc = 0.f;
        #pragma unroll 8
        for (int j = 0; j < H_DIM; ++j) acc += key_w[t * H_DIM + j] * attn_w[H_DIM + j];
        kv[t] = acc;
    }
    __syncthreads();
    float acc = 0.f;
    #pragma unroll 8
    for (int h = 0; h < H_DIM; ++h) acc += embed_w[t * H_DIM + h] * kv[h];
    u[t] = acc;
}

// ---------------- pass 1: stream X (1KB/wave/iter); scores -> out; online partials ----------------
__global__ __launch_bounds__(256) void k_pass1(
    const float* __restrict__ X,        // [N][128]
    const float* __restrict__ u,        // [128]
    float* __restrict__ scores_out,     // [N]
    float* __restrict__ pm,             // [NBLK]
    float* __restrict__ pz,             // [NBLK]
    float* __restrict__ pt_t,           // [128][NBLK]  (transposed partials)
    int N)
{
    const int lane = threadIdx.x & 63;
    const int li   = lane & 31;         // lane within half-wave
    const int half = lane >> 5;         // which row of the pair
    const int w    = threadIdx.x >> 6;  // wave in block
    const int gw   = blockIdx.x * 4 + w;
    const int W    = NBLK * 4;
    const int pairs = (N + 1) >> 1;

    const float4 u4 = *(const float4*)(u + 4 * li);

    float  m = -1e30f, Z = 0.f;
    float4 t = make_float4(0.f, 0.f, 0.f, 0.f);

    int pr = gw;
    float4 x = make_float4(0.f, 0.f, 0.f, 0.f);
    if (pr < pairs) {
        const int row  = 2 * pr + half;
        const int rowc = row < N ? row : N - 1;
        x = *(const float4*)(X + (size_t)rowc * S_DIM + 4 * li);
    }

    while (pr < pairs) {
        const int npr = pr + W;
        float4 xn;
        if (npr < pairs) {                 // prefetch next pair (wave-uniform branch)
            const int row  = 2 * npr + half;
            const int rowc = row < N ? row : N - 1;
            xn = *(const float4*)(X + (size_t)rowc * S_DIM + 4 * li);
        }

        // dot + 32-lane butterfly (uniform within each half)
        float p = x.x * u4.x + x.y * u4.y + x.z * u4.z + x.w * u4.w;
        p += __shfl_xor(p, 1);
        p += __shfl_xor(p, 2);
        p += __shfl_xor(p, 4);
        p += __shfl_xor(p, 8);
        p += __shfl_xor(p, 16);

        const int   row = 2 * pr + half;
        const float s   = (row < N) ? p : -INFINITY;   // mask odd-N tail
        if (li == 0 && row < N) scores_out[row] = s;

        // branchless online-softmax update (exp(-1e30)=0 handles first iter)
        const float mn = fmaxf(m, s);
        const float rs = __expf(m - mn);
        const float e  = __expf(s - mn);
        Z   = Z * rs + e;
        t.x = t.x * rs + e * x.x;
        t.y = t.y * rs + e * x.y;
        t.z = t.z * rs + e * x.z;
        t.w = t.w * rs + e * x.w;
        m   = mn;

        x = xn; pr = npr;
    }

    // merge 8 half-states (4 waves x 2 halves) in LDS
    __shared__ float sT[8][S_DIM];
    __shared__ float sm[8], sZ[8];
    const int hs = w * 2 + half;
    sT[hs][4 * li + 0] = t.x;
    sT[hs][4 * li + 1] = t.y;
    sT[hs][4 * li + 2] = t.z;
    sT[hs][4 * li + 3] = t.w;
    if (li == 0) { sm[hs] = m; sZ[hs] = Z; }
    __syncthreads();

    float mb = sm[0];
    #pragma unroll
    for (int h = 1; h < 8; ++h) mb = fmaxf(mb, sm[h]);

    const int k = threadIdx.x;
    if (k < S_DIM) {
        float acc = 0.f;
        #pragma unroll
        for (int h = 0; h < 8; ++h) acc += sT[h][k] * __expf(sm[h] - mb);
        pt_t[(size_t)k * NBLK + blockIdx.x] = acc;   // transposed for coalesced pass2 reads
    }
    if (k == 0) {
        float Zb = 0.f;
        #pragma unroll
        for (int h = 0; h < 8; ++h) Zb += sZ[h] * __expf(sm[h] - mb);
        pm[blockIdx.x] = mb;
        pz[blockIdx.x] = Zb;
    }
}

// ---------------- pass 2: 128 blocks; each recomputes m*,Z* (16KB) and reduces one k-column ----------------
__global__ __launch_bounds__(256) void k_pass2(
    const float* __restrict__ pm, const float* __restrict__ pz,
    const float* __restrict__ pt_t,
    float* __restrict__ tS,     // [128] normalized weighted input sum
    float* __restrict__ mz)     // [2]
{
    const int k   = blockIdx.x;   // 0..127
    const int tid = threadIdx.x;
    __shared__ float red[256];

    float m = -1e30f;
    for (int b = tid; b < NBLK; b += 256) m = fmaxf(m, pm[b]);
    red[tid] = m; __syncthreads();
    for (int s = 128; s; s >>= 1) { if (tid < s) red[tid] = fmaxf(red[tid], red[tid + s]); __syncthreads(); }
    const float mstar = red[0]; __syncthreads();

    float z = 0.f, tacc = 0.f;
    for (int b = tid; b < NBLK; b += 256) {
        const float sc = __expf(pm[b] - mstar);
        z    += pz[b] * sc;
        tacc += pt_t[(size_t)k * NBLK + b] * sc;
    }
    red[tid] = z; __syncthreads();
    for (int s = 128; s; s >>= 1) { if (tid < s) red[tid] += red[tid + s]; __syncthreads(); }
    const float Zstar = red[0]; __syncthreads();

    red[tid] = tacc; __syncthreads();
    for (int s = 128; s; s >>= 1) { if (tid < s) red[tid] += red[tid + s]; __syncthreads(); }
    if (tid == 0) {
        tS[k] = red[0] / Zstar;
        if (k == 0) { mz[0] = mstar; mz[1] = Zstar; }
    }
}

// ---------------- pass 2c: weighted_embedding = tS @ embed_w + embed_b (tiny) ----------------
__global__ void k_emb(const float* __restrict__ tS, const float* __restrict__ embed_w,
                      const float* __restrict__ embed_b, float* __restrict__ out_emb)
{
    const int h = threadIdx.x;  // 0..63
    float acc = embed_b[h];
    #pragma unroll 8
    for (int k = 0; k < S_DIM; ++k) acc += tS[k] * embed_w[k * H_DIM + h];
    out_emb[h] = acc;
}

// ---------------- pass 3: weights = exp(s - m*)/Z*, in place, float4 ----------------
__global__ __launch_bounds__(256) void k_pass3(
    float* __restrict__ sw, const float* __restrict__ mz, int N)
{
    const float mstar = mz[0];
    const float invZ  = 1.0f / mz[1];
    const int n4 = N >> 2;
    const int stride = gridDim.x * blockDim.x;
    for (int i = blockIdx.x * blockDim.x + threadIdx.x; i < n4; i += stride) {
        float4 v = ((float4*)sw)[i];
        v.x = __expf(v.x - mstar) * invZ;
        v.y = __expf(v.y - mstar) * invZ;
        v.z = __expf(v.z - mstar) * invZ;
        v.w = __expf(v.w - mstar) * invZ;
        ((float4*)sw)[i] = v;
    }
    if (blockIdx.x == 0 && threadIdx.x == 0) {
        for (int i = n4 << 2; i < N; ++i) sw[i] = __expf(sw[i] - mstar) * invZ;
    }
}

extern "C" void kernel_launch(void* const* d_in, const int* in_sizes, int n_in,
                              void* d_out, int out_size, void* d_ws, size_t ws_size,
                              hipStream_t stream) {
    const float* X       = (const float*)d_in[1];   // neighbor_states [N][128]
    const float* embed_w = (const float*)d_in[2];   // [128][64]
    const float* embed_b = (const float*)d_in[3];   // [64]
    const float* key_w   = (const float*)d_in[4];   // [64][64]
    const float* attn_w  = (const float*)d_in[8];   // [128][1]
    float* out = (float*)d_out;                     // [64 + N] fp32

    const int N = in_sizes[1] / S_DIM;              // 500000

    // ws layout (floats): u[128] | mz[2] | tS[128] | pad | pm[NBLK] | pz[NBLK] | pt_t[128*NBLK]
    float* ws   = (float*)d_ws;
    float* u    = ws;                // 128
    float* mz   = ws + 128;          // 2
    float* tS   = ws + 192;          // 128
    float* pm   = ws + 512;          // NBLK
    float* pz   = pm + NBLK;         // NBLK
    float* pt_t = pz + NBLK;         // 128*NBLK  (~1 MB)

    float* out_emb = out;            // [64]
    float* out_w   = out + H_DIM;    // [N] — raw scores parked here, rewritten by pass3

    k_precompute_u<<<1, 128, 0, stream>>>(embed_w, key_w, attn_w, u);
    k_pass1<<<NBLK, 256, 0, stream>>>(X, u, out_w, pm, pz, pt_t, N);
    k_pass2<<<S_DIM, 256, 0, stream>>>(pm, pz, pt_t, tS, mz);
    k_emb<<<1, H_DIM, 0, stream>>>(tS, embed_w, embed_b, out_emb);
    k_pass3<<<((N >> 2) + 255) / 256, 256, 0, stream>>>(out_w, mz, N);
}